// Round 4
// baseline (2229.305 us; speedup 1.0000x reference)
//
#include <hip/hip_runtime.h>
#include <math.h>

#define N_NODES 100000
#define N_BASE  5000
#define N_EDGES 3200000
#define TILE    128                      // dest nodes per gather block
#define NB1     ((N_NODES + 255) / 256)  // 391 scan blocks

// ---------------------------------------------------------------------------
// k_init0: zero deg + scalar accumulator
// ---------------------------------------------------------------------------
__global__ __launch_bounds__(256) void k_init0(int* __restrict__ deg, float* __restrict__ sumb) {
    int i = blockIdx.x * 256 + threadIdx.x;
    if (i < N_NODES) deg[i] = 0;
    if (i == 0) sumb[0] = 0.0f;
}

// deg[col[e]] += 1 (int atomics, once)
__global__ __launch_bounds__(256) void k_count(const int* __restrict__ col, int* __restrict__ deg) {
    int e = blockIdx.x * 256 + threadIdx.x;
    if (e < N_EDGES) atomicAdd(&deg[col[e]], 1);
}

// ---------------------------------------------------------------------------
// 3-kernel coalesced scan: deg -> rowptr (exclusive), cursor=rowptr, dinv
// ---------------------------------------------------------------------------
__global__ __launch_bounds__(256) void k_scan1(const int* __restrict__ deg, int* __restrict__ intra,
                                               int* __restrict__ bsum) {
    __shared__ int sh[256];
    int t = threadIdx.x;
    int i = blockIdx.x * 256 + t;
    int v = (i < N_NODES) ? deg[i] : 0;
    sh[t] = v;
    __syncthreads();
    for (int off = 1; off < 256; off <<= 1) {
        int u = (t >= off) ? sh[t - off] : 0;
        __syncthreads();
        sh[t] += u;
        __syncthreads();
    }
    if (i < N_NODES) intra[i] = sh[t] - v;   // intra-block exclusive prefix
    if (t == 255) bsum[blockIdx.x] = sh[255];
}

__global__ __launch_bounds__(512) void k_scan2(int* __restrict__ bsum) {
    __shared__ int sh[512];
    int t = threadIdx.x;
    int v = (t < NB1) ? bsum[t] : 0;
    sh[t] = v;
    __syncthreads();
    for (int off = 1; off < 512; off <<= 1) {
        int u = (t >= off) ? sh[t - off] : 0;
        __syncthreads();
        sh[t] += u;
        __syncthreads();
    }
    if (t < NB1) bsum[t] = sh[t] - v;        // exclusive block offsets
}

__global__ __launch_bounds__(256) void k_scan3(const int* __restrict__ deg, int* __restrict__ rowptr,
                                               const int* __restrict__ bsum, int* __restrict__ cursor,
                                               float* __restrict__ dinv) {
    int i = blockIdx.x * 256 + threadIdx.x;
    if (i < N_NODES) {
        int r = rowptr[i] + bsum[i >> 8];    // rowptr holds intra prefix (aliased, same-slot RMW)
        rowptr[i] = r;
        cursor[i] = r;
        dinv[i] = rsqrtf((float)(deg[i] + 1));  // +1 self loop
    }
    if (i == 0) rowptr[N_NODES] = N_EDGES;
}

// ---------------------------------------------------------------------------
// k_fill: csr[pos] = (local_dest << 17) | src, grouped by destination.
// cursor pre-initialized to rowptr, so no rowptr load here.
// ---------------------------------------------------------------------------
__global__ __launch_bounds__(256) void k_fill(const int* __restrict__ row, const int* __restrict__ col,
                                              int* __restrict__ cursor, unsigned* __restrict__ csr) {
    int e = blockIdx.x * 256 + threadIdx.x;
    if (e >= N_EDGES) return;
    int d = col[e];
    int pos = atomicAdd(&cursor[d], 1);
    csr[pos] = (unsigned)row[e] | ((unsigned)(d & (TILE - 1)) << 17);
}

// ---------------------------------------------------------------------------
// k_ab_h: bb = [x1 | tile(x2)] @ W4^T + b4           (stride 20)
//         h0 = dinv * (Wg @ [relu(x1@W1^T+b1) | bb]) (stride 16, h0[15]=0)
// ---------------------------------------------------------------------------
__global__ __launch_bounds__(256) void k_ab_h(const float* __restrict__ x1, const float* __restrict__ x2,
                                              const float* __restrict__ W1, const float* __restrict__ b1,
                                              const float* __restrict__ W4, const float* __restrict__ b4,
                                              const float* __restrict__ Wg, const float* __restrict__ dinv,
                                              float* __restrict__ bb, float* __restrict__ h0) {
    __shared__ float sW1[225], sb1[15], sW4[361], sb4[19], sWg[510];
    for (int t = threadIdx.x; t < 225; t += 256) sW1[t] = W1[t];
    for (int t = threadIdx.x; t < 361; t += 256) sW4[t] = W4[t];
    for (int t = threadIdx.x; t < 510; t += 256) sWg[t] = Wg[t];
    if (threadIdx.x < 15) sb1[threadIdx.x] = b1[threadIdx.x];
    if (threadIdx.x < 19) sb4[threadIdx.x] = b4[threadIdx.x];
    __syncthreads();
    int i = blockIdx.x * 256 + threadIdx.x;
    if (i >= N_NODES) return;
    float x[15];
#pragma unroll
    for (int k = 0; k < 15; k++) x[k] = x1[(size_t)i * 15 + k];
    float xt[4];
    int ib = i % N_BASE;
#pragma unroll
    for (int k = 0; k < 4; k++) xt[k] = x2[(size_t)ib * 4 + k];
    float in[34];
#pragma unroll
    for (int o = 0; o < 19; o++) {
        float s = sb4[o];
#pragma unroll
        for (int k = 0; k < 15; k++) s += x[k] * sW4[o * 19 + k];
#pragma unroll
        for (int k = 0; k < 4; k++) s += xt[k] * sW4[o * 19 + 15 + k];
        bb[(size_t)i * 20 + o] = s;
        in[15 + o] = s;
    }
#pragma unroll
    for (int o = 0; o < 15; o++) {
        float s = sb1[o];
#pragma unroll
        for (int k = 0; k < 15; k++) s += x[k] * sW1[o * 15 + k];
        in[o] = fmaxf(s, 0.0f);
    }
    float dn = dinv[i];
#pragma unroll
    for (int o = 0; o < 15; o++) {
        float s = 0.0f;
#pragma unroll
        for (int k = 0; k < 34; k++) s += in[k] * sWg[o * 34 + k];
        h0[(size_t)i * 16 + o] = s * dn;
    }
    h0[(size_t)i * 16 + 15] = 0.0f;
}

// ---------------------------------------------------------------------------
// k_gather: block owns TILE dest nodes (contiguous CSR range).
//   Phase 1: LDS-accumulate neighbor h' rows (4 lanes/edge, float4 gathers).
//   Phase 2: agg = dinv*(h'_self + sum); fused relu+bias and either
//            next h' = dinv*(Wg@[a|bb])  or  (last) W3 projection + reduce.
// ---------------------------------------------------------------------------
__global__ __launch_bounds__(256) void k_gather(const int* __restrict__ rowptr,
                                                const unsigned* __restrict__ csr,
                                                const float* __restrict__ h_in,
                                                const float* __restrict__ dinv,
                                                const float* __restrict__ bb,
                                                const float* __restrict__ Wg,
                                                const float* __restrict__ bg,
                                                const float* __restrict__ W3,
                                                float* __restrict__ h_out,
                                                float* __restrict__ sumb, int last) {
    __shared__ float sagg[TILE * 17];   // stride 17: conflict-free epilogue reads
    __shared__ float sW[510], sbg[15], sW3[34];
    int t = threadIdx.x;
    int n0 = blockIdx.x * TILE;
    for (int k = t; k < 510; k += 256) sW[k] = Wg[k];
    if (t < 15) sbg[t] = bg[t];
    if (t >= 32 && t < 66) sW3[t - 32] = W3[t - 32];
    for (int k = t; k < TILE * 17; k += 256) sagg[k] = 0.0f;
    int nEnd = n0 + TILE; if (nEnd > N_NODES) nEnd = N_NODES;
    int eStart = rowptr[n0];
    int eEnd = rowptr[nEnd];
    __syncthreads();

    int sub = t & 3;                       // channel quad (4 floats)
    for (int j = eStart + (t >> 2); j < eEnd; j += 64) {
        unsigned p = csr[j];
        int src = (int)(p & 0x1FFFFu);
        int ld  = (int)(p >> 17);
        float4 hv = *(const float4*)(h_in + (size_t)src * 16 + sub * 4);
        float* dst = sagg + ld * 17 + sub * 4;
        atomicAdd(dst + 0, hv.x);
        atomicAdd(dst + 1, hv.y);
        atomicAdd(dst + 2, hv.z);
        atomicAdd(dst + 3, hv.w);
    }
    __syncthreads();

    float val = 0.0f;
    int node = n0 + t;
    if (t < TILE && node < N_NODES) {
        float dn = dinv[node];
        float in[34];
#pragma unroll
        for (int k = 0; k < 15; k++) {
            float v = dn * (h_in[(size_t)node * 16 + k] + sagg[t * 17 + k]);
            in[k] = fmaxf(v + sbg[k], 0.0f);
        }
#pragma unroll
        for (int k = 0; k < 19; k++) in[15 + k] = bb[(size_t)node * 20 + k];
        if (!last) {
#pragma unroll
            for (int o = 0; o < 15; o++) {
                float s = 0.0f;
#pragma unroll
                for (int k = 0; k < 34; k++) s += in[k] * sW[o * 34 + k];
                h_out[(size_t)node * 16 + o] = s * dn;
            }
            h_out[(size_t)node * 16 + 15] = 0.0f;
        } else {
            float s = 0.0f;
#pragma unroll
            for (int k = 0; k < 34; k++) s += in[k] * sW3[k];
            val = s;
        }
    }
    if (last) {
#pragma unroll
        for (int off = 32; off > 0; off >>= 1) val += __shfl_down(val, off, 64);
        __shared__ float ws2[4];
        if ((t & 63) == 0) ws2[t >> 6] = val;
        __syncthreads();
        if (t == 0) atomicAdd(sumb, ws2[0] + ws2[1] + ws2[2] + ws2[3]);
    }
}

__global__ void k_finalize(const float* __restrict__ sumb, const float* __restrict__ b3,
                           float* __restrict__ out) {
    out[0] = tanhf(sumb[0] * (1.0f / (float)N_NODES) + b3[0]);
}

// ---------------------------------------------------------------------------
extern "C" void kernel_launch(void* const* d_in, const int* in_sizes, int n_in,
                              void* d_out, int out_size, void* d_ws, size_t ws_size,
                              hipStream_t stream) {
    const float* x1 = (const float*)d_in[0];
    const float* x2 = (const float*)d_in[1];
    const int* edges = (const int*)d_in[2];
    const float* W1 = (const float*)d_in[3];
    const float* b1 = (const float*)d_in[4];
    const float* Wg = (const float*)d_in[5];
    const float* bg = (const float*)d_in[6];
    const float* W3 = (const float*)d_in[7];
    const float* b3 = (const float*)d_in[8];
    const float* W4 = (const float*)d_in[9];
    const float* b4 = (const float*)d_in[10];

    const int* row = edges;             // edges[0]
    const int* col = edges + N_EDGES;   // edges[1]

    // workspace layout (4-byte words)
    char* ws = (char*)d_ws;
    int*      deg    = (int*)ws;                               // N
    int*      cursor = deg + N_NODES;                          // N
    int*      rowptr = cursor + N_NODES;                       // N+1
    int*      bsum   = rowptr + (N_NODES + 1);                 // 512
    unsigned* csr    = (unsigned*)(bsum + 512);                // E
    float*    dinv   = (float*)(csr + N_EDGES);                // N
    float*    bb     = dinv + N_NODES;                         // N*20
    float*    h0     = bb + (size_t)N_NODES * 20;              // N*16
    float*    h1     = h0 + (size_t)N_NODES * 16;              // N*16
    float*    sumb   = h1 + (size_t)N_NODES * 16;              // 1

    int gN = (N_NODES + 255) / 256;
    int gE = (N_EDGES + 255) / 256;
    int gT = (N_NODES + TILE - 1) / TILE;

    k_init0<<<gN, 256, 0, stream>>>(deg, sumb);
    k_count<<<gE, 256, 0, stream>>>(col, deg);
    k_scan1<<<NB1, 256, 0, stream>>>(deg, rowptr, bsum);
    k_scan2<<<1, 512, 0, stream>>>(bsum);
    k_scan3<<<gN, 256, 0, stream>>>(deg, rowptr, bsum, cursor, dinv);
    k_fill<<<gE, 256, 0, stream>>>(row, col, cursor, csr);
    k_ab_h<<<gN, 256, 0, stream>>>(x1, x2, W1, b1, W4, b4, Wg, dinv, bb, h0);
    for (int t = 0; t < 5; t++) {
        const float* hi = (t & 1) ? h1 : h0;
        float* ho = (t & 1) ? h0 : h1;
        k_gather<<<gT, 256, 0, stream>>>(rowptr, csr, hi, dinv, bb, Wg, bg, W3,
                                         ho, sumb, t == 4 ? 1 : 0);
    }
    k_finalize<<<1, 1, 0, stream>>>(sumb, b3, (float*)d_out);
}

// Round 5
// 1330.552 us; speedup vs baseline: 1.6755x; 1.6755x over previous
//
#include <hip/hip_runtime.h>
#include <math.h>

#define N_NODES 100000
#define N_BASE  5000
#define N_EDGES 3200000
#define NT      782        // dest tiles of 128 nodes
#define CAP     6144       // csr slots per tile (mean 4092, sigma 64 -> 32 sigma headroom)
#define SENT    100000u    // sentinel src -> h row N (always zero)

// ---------------------------------------------------------------------------
// k_init: cursor[b] = b*CAP, bins=0, zero h0/h1 sentinel row N
// ---------------------------------------------------------------------------
__global__ __launch_bounds__(1024) void k_init(int* __restrict__ cursor, float* __restrict__ bins,
                                               float* __restrict__ h0, float* __restrict__ h1) {
    int t = threadIdx.x;
    if (t < NT) cursor[t] = t * CAP;
    if (t < 64) bins[t] = 0.0f;
    if (t < 16) { h0[(size_t)N_NODES * 16 + t] = 0.0f; h1[(size_t)N_NODES * 16 + t] = 0.0f; }
}

// ---------------------------------------------------------------------------
// k_pass1: bucket edges by dest tile; packed word = (dest&127)<<17 | src
// ---------------------------------------------------------------------------
__global__ __launch_bounds__(256) void k_pass1(const int* __restrict__ row, const int* __restrict__ col,
                                               int* __restrict__ cursor, unsigned* __restrict__ csr) {
    int e = blockIdx.x * 256 + threadIdx.x;
    if (e >= N_EDGES) return;
    int d = col[e];
    int s = row[e];
    int pos = atomicAdd(&cursor[d >> 7], 1);
    csr[pos] = (unsigned)s | ((unsigned)(d & 127) << 17);
}

// ---------------------------------------------------------------------------
// k_pass2: per-tile LDS counting sort -> csr grouped by dest, per-node runs
// padded to x4 with SENT; writes rs/re (padded) and dinv.
// ---------------------------------------------------------------------------
__global__ __launch_bounds__(256) void k_pass2(const int* __restrict__ cursor, unsigned* __restrict__ csr,
                                               int* __restrict__ rs, int* __restrict__ re,
                                               float* __restrict__ dinv) {
    __shared__ int cnts[128], offs[128], cur[128];
    __shared__ unsigned sorted[CAP];
    int t = threadIdx.x, b = blockIdx.x;
    int base = b * CAP;
    int cnt = cursor[b] - base;
    if (t < 128) cnts[t] = 0;
    __syncthreads();
    for (int j = t; j < cnt; j += 256) atomicAdd(&cnts[csr[base + j] >> 17], 1);
    __syncthreads();
    if (t < 128) offs[t] = (cnts[t] + 3) & ~3;   // padded count
    __syncthreads();
    for (int off = 1; off < 128; off <<= 1) {    // inclusive scan of padded counts
        int v = 0;
        if (t < 128 && t >= off) v = offs[t - off];
        __syncthreads();
        if (t < 128) offs[t] += v;
        __syncthreads();
    }
    if (t < 128) {
        int deg = cnts[t], pc = (deg + 3) & ~3;
        int excl = offs[t] - pc;
        cur[t] = excl;
        int node = b * 128 + t;
        if (node < N_NODES) {
            rs[node] = base + excl;
            re[node] = base + excl + pc;
            dinv[node] = rsqrtf((float)(deg + 1));   // +1 self loop
        }
    }
    __syncthreads();
    for (int j = t; j < cnt; j += 256) {
        unsigned p = csr[base + j];
        int slot = atomicAdd(&cur[p >> 17], 1);
        sorted[slot] = p;
    }
    __syncthreads();
    if (t < 128) {
        int deg = cnts[t], pc = (deg + 3) & ~3;
        int excl = offs[t] - pc;
        for (int k = deg; k < pc; k++) sorted[excl + k] = SENT;
    }
    __syncthreads();
    int tot = offs[127];
    for (int j = t; j < tot; j += 256) csr[base + j] = sorted[j];
}

// ---------------------------------------------------------------------------
// k_ab_h: bb = [x1 | tile(x2)] @ W4^T + b4
//         h0 = dinv * (Wg @ [relu(x1@W1^T+b1) | bb])
//         bins += per-node W3[15:34].bb  (iteration-invariant part of output)
// ---------------------------------------------------------------------------
__global__ __launch_bounds__(256) void k_ab_h(const float* __restrict__ x1, const float* __restrict__ x2,
                                              const float* __restrict__ W1, const float* __restrict__ b1,
                                              const float* __restrict__ W4, const float* __restrict__ b4,
                                              const float* __restrict__ Wg, const float* __restrict__ W3,
                                              const float* __restrict__ dinv,
                                              float* __restrict__ bb, float* __restrict__ h0,
                                              float* __restrict__ bins) {
    __shared__ float sW1[225], sb1[15], sW4[361], sb4[19], sWg[510], sW3b[19];
    for (int t = threadIdx.x; t < 225; t += 256) sW1[t] = W1[t];
    for (int t = threadIdx.x; t < 361; t += 256) sW4[t] = W4[t];
    for (int t = threadIdx.x; t < 510; t += 256) sWg[t] = Wg[t];
    if (threadIdx.x < 15) sb1[threadIdx.x] = b1[threadIdx.x];
    if (threadIdx.x < 19) { sb4[threadIdx.x] = b4[threadIdx.x]; sW3b[threadIdx.x] = W3[15 + threadIdx.x]; }
    __syncthreads();
    int i = blockIdx.x * 256 + threadIdx.x;
    bool valid = i < N_NODES;
    int ii = valid ? i : 0;
    float x[15];
#pragma unroll
    for (int k = 0; k < 15; k++) x[k] = x1[(size_t)ii * 15 + k];
    float xt[4];
    int ib = ii % N_BASE;
#pragma unroll
    for (int k = 0; k < 4; k++) xt[k] = x2[(size_t)ib * 4 + k];
    float in[34];
    float bp = 0.0f;
#pragma unroll
    for (int o = 0; o < 19; o++) {
        float s = sb4[o];
#pragma unroll
        for (int k = 0; k < 15; k++) s += x[k] * sW4[o * 19 + k];
#pragma unroll
        for (int k = 0; k < 4; k++) s += xt[k] * sW4[o * 19 + 15 + k];
        in[15 + o] = s;
        bp += s * sW3b[o];
        if (valid) bb[(size_t)ii * 20 + o] = s;
    }
#pragma unroll
    for (int o = 0; o < 15; o++) {
        float s = sb1[o];
#pragma unroll
        for (int k = 0; k < 15; k++) s += x[k] * sW1[o * 15 + k];
        in[o] = fmaxf(s, 0.0f);
    }
    float dn = dinv[ii];
    if (valid) {
#pragma unroll
        for (int o = 0; o < 15; o++) {
            float s = 0.0f;
#pragma unroll
            for (int k = 0; k < 34; k++) s += in[k] * sWg[o * 34 + k];
            h0[(size_t)ii * 16 + o] = s * dn;
        }
        h0[(size_t)ii * 16 + 15] = 0.0f;
    }
    // block-reduce bp -> bins
    float val = valid ? bp : 0.0f;
#pragma unroll
    for (int off = 32; off > 0; off >>= 1) val += __shfl_down(val, off, 64);
    __shared__ float wsum[4];
    if ((threadIdx.x & 63) == 0) wsum[threadIdx.x >> 6] = val;
    __syncthreads();
    if (threadIdx.x == 0) atomicAdd(&bins[blockIdx.x & 63], wsum[0] + wsum[1] + wsum[2] + wsum[3]);
}

// ---------------------------------------------------------------------------
// k_gather: one wave per dest node. One coalesced csr chunk load, shfl-
// broadcast edges, 4 quarters x 16ch h-row reads (independent, pipelined).
// Fused epilogue: relu(dinv*(h_self+acc)+bg) then next h' (or last: W3.a).
// ---------------------------------------------------------------------------
__global__ __launch_bounds__(256) void k_gather(const int* __restrict__ rs, const int* __restrict__ re,
                                                const unsigned* __restrict__ csr,
                                                const float* __restrict__ h_in,
                                                const float* __restrict__ dinv,
                                                const float* __restrict__ bb,
                                                const float* __restrict__ Wg,
                                                const float* __restrict__ bg,
                                                const float* __restrict__ W3,
                                                float* __restrict__ h_out,
                                                float* __restrict__ bins, int last) {
    __shared__ float sWg[544], sbg[16], sW3[16];
    __shared__ float ws2[4];
    int t = threadIdx.x;
    for (int k = t; k < 544; k += 256) sWg[k] = (k < 510) ? Wg[k] : 0.0f;
    if (t < 16) { sbg[t] = (t < 15) ? bg[t] : 0.0f; sW3[t] = (t < 15) ? W3[t] : 0.0f; }
    __syncthreads();
    int node = blockIdx.x * 4 + (t >> 6);
    int lane = t & 63, ch = lane & 15, q = lane >> 4;
    int start = rs[node];
    int pdeg = re[node] - start;    // padded degree (multiple of 4)
    float acc = 0.0f;
    for (int base = 0; base < pdeg; base += 64) {
        int rem = pdeg - base;
        unsigned ce = SENT;
        if (lane < rem) ce = csr[start + base + lane];
        int lim = rem < 64 ? rem : 64;
#pragma unroll 4
        for (int e0 = q; e0 < lim; e0 += 4) {
            unsigned p = __shfl(ce, e0, 64);
            acc += h_in[(size_t)(p & 0x1FFFFu) * 16 + ch];
        }
    }
    acc += __shfl_xor(acc, 16, 64);
    acc += __shfl_xor(acc, 32, 64);
    float dn = dinv[node];
    float hs = h_in[(size_t)node * 16 + ch];
    float aval = fmaxf(dn * (hs + acc) + sbg[ch], 0.0f);   // a[ch]; ch==15 -> 0
    if (!last) {
        float ink[15];
#pragma unroll
        for (int k = 0; k < 15; k++) ink[k] = __shfl(aval, k, 64);
        const float4* bp4 = (const float4*)(bb + (size_t)node * 20);
        float4 q0 = bp4[0], q1 = bp4[1], q2 = bp4[2], q3 = bp4[3], q4 = bp4[4];
        float bv[19] = {q0.x, q0.y, q0.z, q0.w, q1.x, q1.y, q1.z, q1.w,
                        q2.x, q2.y, q2.z, q2.w, q3.x, q3.y, q3.z, q3.w,
                        q4.x, q4.y, q4.z};
        float s = 0.0f;
#pragma unroll
        for (int k = 0; k < 15; k++) s += ink[k] * sWg[ch * 34 + k];
#pragma unroll
        for (int k = 0; k < 19; k++) s += bv[k] * sWg[ch * 34 + 15 + k];
        if (q == 0) h_out[(size_t)node * 16 + ch] = s * dn;   // ch==15 row: sWg pad -> 0
    } else {
        float c = aval * sW3[ch];
        c += __shfl_xor(c, 8, 64);
        c += __shfl_xor(c, 4, 64);
        c += __shfl_xor(c, 2, 64);
        c += __shfl_xor(c, 1, 64);
        if (lane == 0) ws2[t >> 6] = c;
        __syncthreads();
        if (t == 0) atomicAdd(&bins[blockIdx.x & 63], ws2[0] + ws2[1] + ws2[2] + ws2[3]);
    }
}

__global__ void k_finalize(const float* __restrict__ bins, const float* __restrict__ b3,
                           float* __restrict__ out) {
    float s = 0.0f;
    for (int k = 0; k < 64; k++) s += bins[k];
    out[0] = tanhf(s * (1.0f / (float)N_NODES) + b3[0]);
}

// ---------------------------------------------------------------------------
extern "C" void kernel_launch(void* const* d_in, const int* in_sizes, int n_in,
                              void* d_out, int out_size, void* d_ws, size_t ws_size,
                              hipStream_t stream) {
    const float* x1 = (const float*)d_in[0];
    const float* x2 = (const float*)d_in[1];
    const int* edges = (const int*)d_in[2];
    const float* W1 = (const float*)d_in[3];
    const float* b1 = (const float*)d_in[4];
    const float* Wg = (const float*)d_in[5];
    const float* bg = (const float*)d_in[6];
    const float* W3 = (const float*)d_in[7];
    const float* b3 = (const float*)d_in[8];
    const float* W4 = (const float*)d_in[9];
    const float* b4 = (const float*)d_in[10];

    const int* row = edges;             // edges[0]
    const int* col = edges + N_EDGES;   // edges[1]

    // workspace layout (all sub-arrays 64B-aligned by construction)
    char* ws = (char*)d_ws;
    unsigned* csr  = (unsigned*)ws;                              // NT*CAP      (19.2 MB)
    float*    bb   = (float*)(csr + (size_t)NT * CAP);           // N*20        (8 MB)
    float*    h0   = bb + (size_t)N_NODES * 20;                  // (N+1)*16    (6.4 MB)
    float*    h1   = h0 + (size_t)(N_NODES + 1) * 16;            // (N+1)*16
    float*    dinv = h1 + (size_t)(N_NODES + 1) * 16;            // N
    int*      rs   = (int*)(dinv + N_NODES);                     // N
    int*      re   = rs + N_NODES;                               // N
    int*      cursor = re + N_NODES;                             // NT
    float*    bins = (float*)(cursor + NT);                      // 64

    int gN = (N_NODES + 255) / 256;
    int gE = (N_EDGES + 255) / 256;

    k_init<<<1, 1024, 0, stream>>>(cursor, bins, h0, h1);
    k_pass1<<<gE, 256, 0, stream>>>(row, col, cursor, csr);
    k_pass2<<<NT, 256, 0, stream>>>(cursor, csr, rs, re, dinv);
    k_ab_h<<<gN, 256, 0, stream>>>(x1, x2, W1, b1, W4, b4, Wg, W3, dinv, bb, h0, bins);
    for (int t = 0; t < 5; t++) {
        const float* hi = (t & 1) ? h1 : h0;
        float* ho = (t & 1) ? h0 : h1;
        k_gather<<<N_NODES / 4, 256, 0, stream>>>(rs, re, csr, hi, dinv, bb, Wg, bg, W3,
                                                  ho, bins, t == 4 ? 1 : 0);
    }
    k_finalize<<<1, 1, 0, stream>>>(bins, b3, (float*)d_out);
}

// Round 8
// 1005.374 us; speedup vs baseline: 2.2174x; 1.3234x over previous
//
#include <hip/hip_runtime.h>
#include <math.h>

#define N_NODES 100000
#define N_BASE  5000
#define N_EDGES 3200000
#define NB1     ((N_NODES + 255) / 256)  // 391 scan blocks

// ---------------------------------------------------------------------------
// k_initd: deg = 0
// ---------------------------------------------------------------------------
__global__ __launch_bounds__(256) void k_initd(int* __restrict__ deg) {
    int i = blockIdx.x * 256 + threadIdx.x;
    if (i < N_NODES) deg[i] = 0;
}

// deg[col[e]] += 1  (100K counters, ~32-deep contention — proven in R2-R4)
__global__ __launch_bounds__(256) void k_count(const int* __restrict__ col, int* __restrict__ deg) {
    int e = blockIdx.x * 256 + threadIdx.x;
    if (e < N_EDGES) atomicAdd(&deg[col[e]], 1);
}

// ---------------------------------------------------------------------------
// 3-kernel coalesced scan: deg -> rowptr (exclusive); cursor = rowptr; dinv
// ---------------------------------------------------------------------------
__global__ __launch_bounds__(256) void k_scan1(const int* __restrict__ deg, int* __restrict__ intra,
                                               int* __restrict__ bsum) {
    __shared__ int sh[256];
    int t = threadIdx.x;
    int i = blockIdx.x * 256 + t;
    int v = (i < N_NODES) ? deg[i] : 0;
    sh[t] = v;
    __syncthreads();
    for (int off = 1; off < 256; off <<= 1) {
        int u = (t >= off) ? sh[t - off] : 0;
        __syncthreads();
        sh[t] += u;
        __syncthreads();
    }
    if (i < N_NODES) intra[i] = sh[t] - v;   // intra-block exclusive prefix
    if (t == 255) bsum[blockIdx.x] = sh[255];
}

__global__ __launch_bounds__(512) void k_scan2(int* __restrict__ bsum, float* __restrict__ bins) {
    __shared__ int sh[512];
    int t = threadIdx.x;
    int v = (t < NB1) ? bsum[t] : 0;
    sh[t] = v;
    __syncthreads();
    for (int off = 1; off < 512; off <<= 1) {
        int u = (t >= off) ? sh[t - off] : 0;
        __syncthreads();
        sh[t] += u;
        __syncthreads();
    }
    if (t < NB1) bsum[t] = sh[t] - v;        // exclusive block offsets
    if (t < 64) bins[t] = 0.0f;
}

__global__ __launch_bounds__(256) void k_scan3(const int* __restrict__ deg, int* __restrict__ rowptr,
                                               const int* __restrict__ bsum, int* __restrict__ cursor,
                                               float* __restrict__ dinv) {
    int i = blockIdx.x * 256 + threadIdx.x;
    if (i < N_NODES) {
        int r = rowptr[i] + bsum[i >> 8];    // rowptr held intra prefix (same-slot RMW)
        rowptr[i] = r;
        cursor[i] = r;
        dinv[i] = rsqrtf((float)(deg[i] + 1));  // +1 self loop
    }
    if (i == 0) rowptr[N_NODES] = N_EDGES;
}

// ---------------------------------------------------------------------------
// k_fill: csr[rowptr[d] + rank] = src — exact CSR grouped by destination
// ---------------------------------------------------------------------------
__global__ __launch_bounds__(256) void k_fill(const int* __restrict__ row, const int* __restrict__ col,
                                              int* __restrict__ cursor, unsigned* __restrict__ csr) {
    int e = blockIdx.x * 256 + threadIdx.x;
    if (e >= N_EDGES) return;
    int d = col[e];
    int pos = atomicAdd(&cursor[d], 1);
    csr[pos] = (unsigned)row[e];
}

// ---------------------------------------------------------------------------
// k_ab_h (R5 verbatim): bb = [x1 | tile(x2)] @ W4^T + b4
//         h0 = dinv * (Wg @ [relu(x1@W1^T+b1) | bb])
//         bins += W3[15:34].bb   (iteration-invariant output part)
// ---------------------------------------------------------------------------
__global__ __launch_bounds__(256) void k_ab_h(const float* __restrict__ x1, const float* __restrict__ x2,
                                              const float* __restrict__ W1, const float* __restrict__ b1,
                                              const float* __restrict__ W4, const float* __restrict__ b4,
                                              const float* __restrict__ Wg, const float* __restrict__ W3,
                                              const float* __restrict__ dinv,
                                              float* __restrict__ bb, float* __restrict__ h0,
                                              float* __restrict__ bins) {
    __shared__ float sW1[225], sb1[15], sW4[361], sb4[19], sWg[510], sW3b[19];
    for (int t = threadIdx.x; t < 225; t += 256) sW1[t] = W1[t];
    for (int t = threadIdx.x; t < 361; t += 256) sW4[t] = W4[t];
    for (int t = threadIdx.x; t < 510; t += 256) sWg[t] = Wg[t];
    if (threadIdx.x < 15) sb1[threadIdx.x] = b1[threadIdx.x];
    if (threadIdx.x < 19) { sb4[threadIdx.x] = b4[threadIdx.x]; sW3b[threadIdx.x] = W3[15 + threadIdx.x]; }
    __syncthreads();
    int i = blockIdx.x * 256 + threadIdx.x;
    bool valid = i < N_NODES;
    int ii = valid ? i : 0;
    float x[15];
#pragma unroll
    for (int k = 0; k < 15; k++) x[k] = x1[(size_t)ii * 15 + k];
    float xt[4];
    int ib = ii % N_BASE;
#pragma unroll
    for (int k = 0; k < 4; k++) xt[k] = x2[(size_t)ib * 4 + k];
    float in[34];
    float bp = 0.0f;
#pragma unroll
    for (int o = 0; o < 19; o++) {
        float s = sb4[o];
#pragma unroll
        for (int k = 0; k < 15; k++) s += x[k] * sW4[o * 19 + k];
#pragma unroll
        for (int k = 0; k < 4; k++) s += xt[k] * sW4[o * 19 + 15 + k];
        in[15 + o] = s;
        bp += s * sW3b[o];
        if (valid) bb[(size_t)ii * 20 + o] = s;
    }
#pragma unroll
    for (int o = 0; o < 15; o++) {
        float s = sb1[o];
#pragma unroll
        for (int k = 0; k < 15; k++) s += x[k] * sW1[o * 15 + k];
        in[o] = fmaxf(s, 0.0f);
    }
    float dn = dinv[ii];
    if (valid) {
#pragma unroll
        for (int o = 0; o < 15; o++) {
            float s = 0.0f;
#pragma unroll
            for (int k = 0; k < 34; k++) s += in[k] * sWg[o * 34 + k];
            h0[(size_t)ii * 16 + o] = s * dn;
        }
        h0[(size_t)ii * 16 + 15] = 0.0f;
    }
    float val = valid ? bp : 0.0f;
#pragma unroll
    for (int off = 32; off > 0; off >>= 1) val += __shfl_down(val, off, 64);
    __shared__ float wsum[4];
    if ((threadIdx.x & 63) == 0) wsum[threadIdx.x >> 6] = val;
    __syncthreads();
    if (threadIdx.x == 0) atomicAdd(&bins[blockIdx.x & 63], wsum[0] + wsum[1] + wsum[2] + wsum[3]);
}

// ---------------------------------------------------------------------------
// k_gather (R5-verbatim core): one wave per dest node.
//   Guarded 64-lane csr chunk load; shfl-broadcast; 4 quarters x 16ch scalar
//   h-row reads. Epilogue: aval = relu(dinv*(h_self+acc)+bg); next
//   h' = dinv*(Wg@[a|bb]) or (last) W3[0:15].a reduced to bins.
// ---------------------------------------------------------------------------
__global__ __launch_bounds__(256) void k_gather(const int* __restrict__ rowptr,
                                                const unsigned* __restrict__ csr,
                                                const float* __restrict__ h_in,
                                                const float* __restrict__ dinv,
                                                const float* __restrict__ bb,
                                                const float* __restrict__ Wg,
                                                const float* __restrict__ bg,
                                                const float* __restrict__ W3,
                                                float* __restrict__ h_out,
                                                float* __restrict__ bins, int last) {
    __shared__ float sWg[544], sbg[16], sW3[16];
    __shared__ float ws2[4];
    int t = threadIdx.x;
    for (int k = t; k < 544; k += 256) sWg[k] = (k < 510) ? Wg[k] : 0.0f;
    if (t < 16) { sbg[t] = (t < 15) ? bg[t] : 0.0f; sW3[t] = (t < 15) ? W3[t] : 0.0f; }
    __syncthreads();
    int node = blockIdx.x * 4 + (t >> 6);
    int lane = t & 63, ch = lane & 15, q = lane >> 4;
    int start = rowptr[node];
    int deg = rowptr[node + 1] - start;
    float acc = 0.0f;
    for (int base = 0; base < deg; base += 64) {
        int rem = deg - base;
        unsigned ce = 0;
        if (lane < rem) ce = csr[start + base + lane];
        int lim = rem < 64 ? rem : 64;
#pragma unroll 4
        for (int e0 = q; e0 < lim; e0 += 4) {
            unsigned p = __shfl(ce, e0, 64);
            acc += h_in[(size_t)(p & 0x1FFFFu) * 16 + ch];
        }
    }
    acc += __shfl_xor(acc, 16, 64);
    acc += __shfl_xor(acc, 32, 64);
    float dn = dinv[node];
    float hs = h_in[(size_t)node * 16 + ch];
    float aval = fmaxf(dn * (hs + acc) + sbg[ch], 0.0f);   // a[ch]; ch==15 -> 0
    if (!last) {
        float ink[15];
#pragma unroll
        for (int k = 0; k < 15; k++) ink[k] = __shfl(aval, k, 64);
        const float4* bp4 = (const float4*)(bb + (size_t)node * 20);
        float4 q0 = bp4[0], q1 = bp4[1], q2 = bp4[2], q3 = bp4[3], q4 = bp4[4];
        float bv[19] = {q0.x, q0.y, q0.z, q0.w, q1.x, q1.y, q1.z, q1.w,
                        q2.x, q2.y, q2.z, q2.w, q3.x, q3.y, q3.z, q3.w,
                        q4.x, q4.y, q4.z};
        float s = 0.0f;
#pragma unroll
        for (int k = 0; k < 15; k++) s += ink[k] * sWg[ch * 34 + k];
#pragma unroll
        for (int k = 0; k < 19; k++) s += bv[k] * sWg[ch * 34 + 15 + k];
        if (q == 0) h_out[(size_t)node * 16 + ch] = s * dn;   // ch==15 row: sWg pad -> 0
    } else {
        float c = aval * sW3[ch];
        c += __shfl_xor(c, 8, 64);
        c += __shfl_xor(c, 4, 64);
        c += __shfl_xor(c, 2, 64);
        c += __shfl_xor(c, 1, 64);
        if (lane == 0) ws2[t >> 6] = c;
        __syncthreads();
        if (t == 0) atomicAdd(&bins[blockIdx.x & 63], ws2[0] + ws2[1] + ws2[2] + ws2[3]);
    }
}

__global__ void k_finalize(const float* __restrict__ bins, const float* __restrict__ b3,
                           float* __restrict__ out) {
    float s = 0.0f;
    for (int k = 0; k < 64; k++) s += bins[k];
    out[0] = tanhf(s * (1.0f / (float)N_NODES) + b3[0]);
}

// ---------------------------------------------------------------------------
extern "C" void kernel_launch(void* const* d_in, const int* in_sizes, int n_in,
                              void* d_out, int out_size, void* d_ws, size_t ws_size,
                              hipStream_t stream) {
    const float* x1 = (const float*)d_in[0];
    const float* x2 = (const float*)d_in[1];
    const int* edges = (const int*)d_in[2];
    const float* W1 = (const float*)d_in[3];
    const float* b1 = (const float*)d_in[4];
    const float* Wg = (const float*)d_in[5];
    const float* bg = (const float*)d_in[6];
    const float* W3 = (const float*)d_in[7];
    const float* b3 = (const float*)d_in[8];
    const float* W4 = (const float*)d_in[9];
    const float* b4 = (const float*)d_in[10];

    const int* row = edges;             // edges[0]
    const int* col = edges + N_EDGES;   // edges[1]

    // workspace layout — ~35.2 MB (proven envelope >= 40.4 MB).
    char* ws = (char*)d_ws;
    float*    bb     = (float*)ws;                               // N*20  (8.0 MB)
    float*    h0     = bb + (size_t)N_NODES * 20;                // N*16  (6.4 MB)
    float*    h1     = h0 + (size_t)N_NODES * 16;                // N*16  (6.4 MB)
    float*    dinv   = h1 + (size_t)N_NODES * 16;                // N
    unsigned* csr    = (unsigned*)(dinv + N_NODES);              // E     (12.8 MB)
    int*      deg    = (int*)(csr + N_EDGES);                    // N
    int*      rowptr = deg + N_NODES;                            // N+1
    int*      cursor = rowptr + N_NODES + 1;                     // N
    int*      bsum   = cursor + N_NODES;                         // 512
    float*    bins   = (float*)(bsum + 512);                     // 64

    int gN = (N_NODES + 255) / 256;
    int gE = (N_EDGES + 255) / 256;

    k_initd<<<gN, 256, 0, stream>>>(deg);
    k_count<<<gE, 256, 0, stream>>>(col, deg);
    k_scan1<<<NB1, 256, 0, stream>>>(deg, rowptr, bsum);
    k_scan2<<<1, 512, 0, stream>>>(bsum, bins);
    k_scan3<<<gN, 256, 0, stream>>>(deg, rowptr, bsum, cursor, dinv);
    k_fill<<<gE, 256, 0, stream>>>(row, col, cursor, csr);
    k_ab_h<<<gN, 256, 0, stream>>>(x1, x2, W1, b1, W4, b4, Wg, W3, dinv, bb, h0, bins);
    for (int t = 0; t < 5; t++) {
        const float* hi = (t & 1) ? h1 : h0;
        float* ho = (t & 1) ? h0 : h1;
        k_gather<<<N_NODES / 4, 256, 0, stream>>>(rowptr, csr, hi, dinv, bb, Wg, bg, W3,
                                                  ho, bins, t == 4 ? 1 : 0);
    }
    k_finalize<<<1, 1, 0, stream>>>(bins, b3, (float*)d_out);
}

// Round 9
// 612.275 us; speedup vs baseline: 3.6410x; 1.6420x over previous
//
#include <hip/hip_runtime.h>
#include <math.h>

#define N_NODES 100000
#define N_BASE  5000
#define N_EDGES 3200000
#define NBKT    391       // dest buckets of 256 nodes; also = ceil(E/8192) edge blocks
#define CAPB    9472      // csr slots per bucket (mean 8184, sigma 90 -> +14 sigma)

// ---------------------------------------------------------------------------
// k_initg: gcur[b] = b*CAPB, bins = 0
// ---------------------------------------------------------------------------
__global__ __launch_bounds__(512) void k_initg(int* __restrict__ gcur, float* __restrict__ bins) {
    int t = threadIdx.x;
    if (t < NBKT) gcur[t] = t * CAPB;
    if (t < 64) bins[t] = 0.0f;
}

// ---------------------------------------------------------------------------
// k_bucket (phase A): 391 blocks x 8192 edges. LDS histogram over 391 dest
// buckets -> LDS scan -> one global chunk reservation per (block,bucket) ->
// direct chunked stores of packed (d&255)<<17 | src. Chunk ~21 edges keeps
// lines mostly full: predicted WRITE ~25 MB vs k_fill's 194 MB.
// ---------------------------------------------------------------------------
__global__ __launch_bounds__(256) void k_bucket(const int* __restrict__ row, const int* __restrict__ col,
                                                int* __restrict__ gcur, unsigned* __restrict__ csr) {
    __shared__ int hist[NBKT], gbase[NBKT], cur[NBKT];
    __shared__ int sc[512];
    int t = threadIdx.x;
    int e0 = blockIdx.x * 8192;
    int cnt = (N_EDGES - e0 < 8192) ? (N_EDGES - e0) : 8192;
    for (int k = t; k < NBKT; k += 256) hist[k] = 0;
    __syncthreads();
    for (int j = t; j < cnt; j += 256) atomicAdd(&hist[col[e0 + j] >> 8], 1);
    __syncthreads();
    // inclusive Hillis scan over 512 slots, 2 per thread
    sc[t] = (t < NBKT) ? hist[t] : 0;
    sc[t + 256] = (t + 256 < NBKT) ? hist[t + 256] : 0;
    __syncthreads();
    for (int off = 1; off < 512; off <<= 1) {
        int v0 = (t >= off) ? sc[t - off] : 0;
        int v1 = sc[t + 256 - off];          // t+256-off >= 0 since off <= 256
        __syncthreads();
        sc[t] += v0;
        sc[t + 256] += v1;
        __syncthreads();
    }
    for (int s = t; s < NBKT; s += 256) {
        cur[s] = sc[s] - hist[s];            // local exclusive offset
        gbase[s] = (hist[s] > 0) ? atomicAdd(&gcur[s], hist[s]) : 0;
    }
    __syncthreads();
    for (int j = t; j < cnt; j += 256) {
        int d = col[e0 + j];
        int s = row[e0 + j];
        int b = d >> 8;
        int slot = atomicAdd(&cur[b], 1);
        int local = slot - (sc[b] - hist[b]);
        csr[gbase[b] + local] = ((unsigned)(d & 255) << 17) | (unsigned)s;
    }
}

// ---------------------------------------------------------------------------
// k_sort (phase B): one block per bucket. LDS counting sort of <= CAPB edges
// by local dest; coalesced write-back of pure-src csr into the bucket's own
// window; emits rs/re (exact runs) and dinv (true degree).
// ---------------------------------------------------------------------------
__global__ __launch_bounds__(256) void k_sort(const int* __restrict__ gcur, unsigned* __restrict__ csr,
                                              int* __restrict__ rs, int* __restrict__ re,
                                              float* __restrict__ dinv) {
    __shared__ unsigned stage[CAPB];
    __shared__ int hist[256], offs[256], cur[256];
    int t = threadIdx.x, b = blockIdx.x;
    int base = b * CAPB;
    int cnt = gcur[b] - base;
    hist[t] = 0;
    for (int j = t; j < cnt; j += 256) stage[j] = csr[base + j];
    __syncthreads();
    for (int j = t; j < cnt; j += 256) atomicAdd(&hist[stage[j] >> 17], 1);
    __syncthreads();
    offs[t] = hist[t];
    __syncthreads();
    for (int off = 1; off < 256; off <<= 1) {
        int v = (t >= off) ? offs[t - off] : 0;
        __syncthreads();
        offs[t] += v;
        __syncthreads();
    }
    int excl = offs[t] - hist[t];
    cur[t] = excl;
    int node = b * 256 + t;
    if (node < N_NODES) {
        rs[node] = base + excl;
        re[node] = base + excl + hist[t];
        dinv[node] = rsqrtf((float)(hist[t] + 1));   // +1 self loop
    }
    __syncthreads();
    for (int j = t; j < cnt; j += 256) {
        unsigned p = stage[j];
        int slot = atomicAdd(&cur[p >> 17], 1);
        csr[base + slot] = p & 0x1FFFFu;             // pure src
    }
}

// ---------------------------------------------------------------------------
// k_ab_h (R8 verbatim): bb = [x1 | tile(x2)] @ W4^T + b4
//         h0 = dinv * (Wg @ [relu(x1@W1^T+b1) | bb])
//         bins += W3[15:34].bb   (iteration-invariant output part)
// ---------------------------------------------------------------------------
__global__ __launch_bounds__(256) void k_ab_h(const float* __restrict__ x1, const float* __restrict__ x2,
                                              const float* __restrict__ W1, const float* __restrict__ b1,
                                              const float* __restrict__ W4, const float* __restrict__ b4,
                                              const float* __restrict__ Wg, const float* __restrict__ W3,
                                              const float* __restrict__ dinv,
                                              float* __restrict__ bb, float* __restrict__ h0,
                                              float* __restrict__ bins) {
    __shared__ float sW1[225], sb1[15], sW4[361], sb4[19], sWg[510], sW3b[19];
    for (int t = threadIdx.x; t < 225; t += 256) sW1[t] = W1[t];
    for (int t = threadIdx.x; t < 361; t += 256) sW4[t] = W4[t];
    for (int t = threadIdx.x; t < 510; t += 256) sWg[t] = Wg[t];
    if (threadIdx.x < 15) sb1[threadIdx.x] = b1[threadIdx.x];
    if (threadIdx.x < 19) { sb4[threadIdx.x] = b4[threadIdx.x]; sW3b[threadIdx.x] = W3[15 + threadIdx.x]; }
    __syncthreads();
    int i = blockIdx.x * 256 + threadIdx.x;
    bool valid = i < N_NODES;
    int ii = valid ? i : 0;
    float x[15];
#pragma unroll
    for (int k = 0; k < 15; k++) x[k] = x1[(size_t)ii * 15 + k];
    float xt[4];
    int ib = ii % N_BASE;
#pragma unroll
    for (int k = 0; k < 4; k++) xt[k] = x2[(size_t)ib * 4 + k];
    float in[34];
    float bp = 0.0f;
#pragma unroll
    for (int o = 0; o < 19; o++) {
        float s = sb4[o];
#pragma unroll
        for (int k = 0; k < 15; k++) s += x[k] * sW4[o * 19 + k];
#pragma unroll
        for (int k = 0; k < 4; k++) s += xt[k] * sW4[o * 19 + 15 + k];
        in[15 + o] = s;
        bp += s * sW3b[o];
        if (valid) bb[(size_t)ii * 20 + o] = s;
    }
#pragma unroll
    for (int o = 0; o < 15; o++) {
        float s = sb1[o];
#pragma unroll
        for (int k = 0; k < 15; k++) s += x[k] * sW1[o * 15 + k];
        in[o] = fmaxf(s, 0.0f);
    }
    float dn = dinv[ii];
    if (valid) {
#pragma unroll
        for (int o = 0; o < 15; o++) {
            float s = 0.0f;
#pragma unroll
            for (int k = 0; k < 34; k++) s += in[k] * sWg[o * 34 + k];
            h0[(size_t)ii * 16 + o] = s * dn;
        }
        h0[(size_t)ii * 16 + 15] = 0.0f;
    }
    float val = valid ? bp : 0.0f;
#pragma unroll
    for (int off = 32; off > 0; off >>= 1) val += __shfl_down(val, off, 64);
    __shared__ float wsum[4];
    if ((threadIdx.x & 63) == 0) wsum[threadIdx.x >> 6] = val;
    __syncthreads();
    if (threadIdx.x == 0) atomicAdd(&bins[blockIdx.x & 63], wsum[0] + wsum[1] + wsum[2] + wsum[3]);
}

// ---------------------------------------------------------------------------
// k_gather (R8 verbatim, rs/re interface): one wave per dest node.
//   Guarded 64-lane csr chunk load; shfl-broadcast; 4 quarters x 16ch scalar
//   h-row reads. Epilogue: aval = relu(dinv*(h_self+acc)+bg); next
//   h' = dinv*(Wg@[a|bb]) or (last) W3[0:15].a reduced to bins.
// ---------------------------------------------------------------------------
__global__ __launch_bounds__(256) void k_gather(const int* __restrict__ rs, const int* __restrict__ re,
                                                const unsigned* __restrict__ csr,
                                                const float* __restrict__ h_in,
                                                const float* __restrict__ dinv,
                                                const float* __restrict__ bb,
                                                const float* __restrict__ Wg,
                                                const float* __restrict__ bg,
                                                const float* __restrict__ W3,
                                                float* __restrict__ h_out,
                                                float* __restrict__ bins, int last) {
    __shared__ float sWg[544], sbg[16], sW3[16];
    __shared__ float ws2[4];
    int t = threadIdx.x;
    for (int k = t; k < 544; k += 256) sWg[k] = (k < 510) ? Wg[k] : 0.0f;
    if (t < 16) { sbg[t] = (t < 15) ? bg[t] : 0.0f; sW3[t] = (t < 15) ? W3[t] : 0.0f; }
    __syncthreads();
    int node = blockIdx.x * 4 + (t >> 6);
    int lane = t & 63, ch = lane & 15, q = lane >> 4;
    int start = rs[node];
    int deg = re[node] - start;
    float acc = 0.0f;
    for (int base = 0; base < deg; base += 64) {
        int rem = deg - base;
        unsigned ce = 0;
        if (lane < rem) ce = csr[start + base + lane];
        int lim = rem < 64 ? rem : 64;
#pragma unroll 4
        for (int e0 = q; e0 < lim; e0 += 4) {
            unsigned p = __shfl(ce, e0, 64);
            acc += h_in[(size_t)(p & 0x1FFFFu) * 16 + ch];
        }
    }
    acc += __shfl_xor(acc, 16, 64);
    acc += __shfl_xor(acc, 32, 64);
    float dn = dinv[node];
    float hs = h_in[(size_t)node * 16 + ch];
    float aval = fmaxf(dn * (hs + acc) + sbg[ch], 0.0f);   // a[ch]; ch==15 -> 0
    if (!last) {
        float ink[15];
#pragma unroll
        for (int k = 0; k < 15; k++) ink[k] = __shfl(aval, k, 64);
        const float4* bp4 = (const float4*)(bb + (size_t)node * 20);
        float4 q0 = bp4[0], q1 = bp4[1], q2 = bp4[2], q3 = bp4[3], q4 = bp4[4];
        float bv[19] = {q0.x, q0.y, q0.z, q0.w, q1.x, q1.y, q1.z, q1.w,
                        q2.x, q2.y, q2.z, q2.w, q3.x, q3.y, q3.z, q3.w,
                        q4.x, q4.y, q4.z};
        float s = 0.0f;
#pragma unroll
        for (int k = 0; k < 15; k++) s += ink[k] * sWg[ch * 34 + k];
#pragma unroll
        for (int k = 0; k < 19; k++) s += bv[k] * sWg[ch * 34 + 15 + k];
        if (q == 0) h_out[(size_t)node * 16 + ch] = s * dn;   // ch==15 row: sWg pad -> 0
    } else {
        float c = aval * sW3[ch];
        c += __shfl_xor(c, 8, 64);
        c += __shfl_xor(c, 4, 64);
        c += __shfl_xor(c, 2, 64);
        c += __shfl_xor(c, 1, 64);
        if (lane == 0) ws2[t >> 6] = c;
        __syncthreads();
        if (t == 0) atomicAdd(&bins[blockIdx.x & 63], ws2[0] + ws2[1] + ws2[2] + ws2[3]);
    }
}

__global__ void k_finalize(const float* __restrict__ bins, const float* __restrict__ b3,
                           float* __restrict__ out) {
    float s = 0.0f;
    for (int k = 0; k < 64; k++) s += bins[k];
    out[0] = tanhf(s * (1.0f / (float)N_NODES) + b3[0]);
}

// ---------------------------------------------------------------------------
extern "C" void kernel_launch(void* const* d_in, const int* in_sizes, int n_in,
                              void* d_out, int out_size, void* d_ws, size_t ws_size,
                              hipStream_t stream) {
    const float* x1 = (const float*)d_in[0];
    const float* x2 = (const float*)d_in[1];
    const int* edges = (const int*)d_in[2];
    const float* W1 = (const float*)d_in[3];
    const float* b1 = (const float*)d_in[4];
    const float* Wg = (const float*)d_in[5];
    const float* bg = (const float*)d_in[6];
    const float* W3 = (const float*)d_in[7];
    const float* b3 = (const float*)d_in[8];
    const float* W4 = (const float*)d_in[9];
    const float* b4 = (const float*)d_in[10];

    const int* row = edges;             // edges[0]
    const int* col = edges + N_EDGES;   // edges[1]

    // workspace layout — ~36.9 MB (proven envelope >= 40.4 MB).
    // csr first; bb/h offsets stay 16B-aligned (word counts divisible by 4).
    char* ws = (char*)d_ws;
    unsigned* csr  = (unsigned*)ws;                              // NBKT*CAPB  (14.81 MB)
    float*    bb   = (float*)(csr + (size_t)NBKT * CAPB);        // N*20       (8.0 MB)
    float*    h0   = bb + (size_t)N_NODES * 20;                  // N*16       (6.4 MB)
    float*    h1   = h0 + (size_t)N_NODES * 16;                  // N*16       (6.4 MB)
    float*    dinv = h1 + (size_t)N_NODES * 16;                  // N
    int*      rs   = (int*)(dinv + N_NODES);                     // N
    int*      re   = rs + N_NODES;                               // N
    int*      gcur = re + N_NODES;                               // NBKT
    float*    bins = (float*)(gcur + NBKT);                      // 64

    int gN = (N_NODES + 255) / 256;                              // 391
    int gE = (N_EDGES + 8191) / 8192;                            // 391

    k_initg<<<1, 512, 0, stream>>>(gcur, bins);
    k_bucket<<<gE, 256, 0, stream>>>(row, col, gcur, csr);
    k_sort<<<NBKT, 256, 0, stream>>>(gcur, csr, rs, re, dinv);
    k_ab_h<<<gN, 256, 0, stream>>>(x1, x2, W1, b1, W4, b4, Wg, W3, dinv, bb, h0, bins);
    for (int t = 0; t < 5; t++) {
        const float* hi = (t & 1) ? h1 : h0;
        float* ho = (t & 1) ? h0 : h1;
        k_gather<<<N_NODES / 4, 256, 0, stream>>>(rs, re, csr, hi, dinv, bb, Wg, bg, W3,
                                                  ho, bins, t == 4 ? 1 : 0);
    }
    k_finalize<<<1, 1, 0, stream>>>(bins, b3, (float*)d_out);
}

// Round 10
// 572.202 us; speedup vs baseline: 3.8960x; 1.0700x over previous
//
#include <hip/hip_runtime.h>
#include <math.h>

#define N_NODES 100000
#define N_BASE  5000
#define N_EDGES 3200000
#define NBKT    391       // dest buckets of 256 nodes; also = ceil(E/8192) edge blocks
#define CAPB    9472      // csr slots per bucket (mean 8184, sigma 90 -> +14 sigma)

// ---------------------------------------------------------------------------
// k_initg: gcur[b] = b*CAPB, bins = 0
// ---------------------------------------------------------------------------
__global__ __launch_bounds__(512) void k_initg(int* __restrict__ gcur, float* __restrict__ bins) {
    int t = threadIdx.x;
    if (t < NBKT) gcur[t] = t * CAPB;
    if (t < 64) bins[t] = 0.0f;
}

// ---------------------------------------------------------------------------
// k_bucket (phase A): 391 blocks x 8192 edges. LDS histogram over 391 dest
// buckets -> LDS scan -> one global chunk reservation per (block,bucket) ->
// direct chunked stores of packed (d&255)<<17 | src.
// ---------------------------------------------------------------------------
__global__ __launch_bounds__(256) void k_bucket(const int* __restrict__ row, const int* __restrict__ col,
                                                int* __restrict__ gcur, unsigned* __restrict__ csr) {
    __shared__ int hist[NBKT], gbase[NBKT], cur[NBKT];
    __shared__ int sc[512];
    int t = threadIdx.x;
    int e0 = blockIdx.x * 8192;
    int cnt = (N_EDGES - e0 < 8192) ? (N_EDGES - e0) : 8192;
    for (int k = t; k < NBKT; k += 256) hist[k] = 0;
    __syncthreads();
    for (int j = t; j < cnt; j += 256) atomicAdd(&hist[col[e0 + j] >> 8], 1);
    __syncthreads();
    // inclusive Hillis scan over 512 slots, 2 per thread
    sc[t] = (t < NBKT) ? hist[t] : 0;
    sc[t + 256] = (t + 256 < NBKT) ? hist[t + 256] : 0;
    __syncthreads();
    for (int off = 1; off < 512; off <<= 1) {
        int v0 = (t >= off) ? sc[t - off] : 0;
        int v1 = sc[t + 256 - off];          // t+256-off >= 0 since off <= 256
        __syncthreads();
        sc[t] += v0;
        sc[t + 256] += v1;
        __syncthreads();
    }
    for (int s = t; s < NBKT; s += 256) {
        cur[s] = sc[s] - hist[s];            // local exclusive offset
        gbase[s] = (hist[s] > 0) ? atomicAdd(&gcur[s], hist[s]) : 0;
    }
    __syncthreads();
    for (int j = t; j < cnt; j += 256) {
        int d = col[e0 + j];
        int s = row[e0 + j];
        int b = d >> 8;
        int slot = atomicAdd(&cur[b], 1);
        int local = slot - (sc[b] - hist[b]);
        csr[gbase[b] + local] = ((unsigned)(d & 255) << 17) | (unsigned)s;
    }
}

// ---------------------------------------------------------------------------
// k_sort (phase B): one block per bucket. LDS counting sort of <= CAPB edges
// by local dest; coalesced write-back of pure-src csr into the bucket's own
// window; emits rs/re (exact runs) and dinv (true degree).
// ---------------------------------------------------------------------------
__global__ __launch_bounds__(256) void k_sort(const int* __restrict__ gcur, unsigned* __restrict__ csr,
                                              int* __restrict__ rs, int* __restrict__ re,
                                              float* __restrict__ dinv) {
    __shared__ unsigned stage[CAPB];
    __shared__ int hist[256], offs[256], cur[256];
    int t = threadIdx.x, b = blockIdx.x;
    int base = b * CAPB;
    int cnt = gcur[b] - base;
    hist[t] = 0;
    for (int j = t; j < cnt; j += 256) stage[j] = csr[base + j];
    __syncthreads();
    for (int j = t; j < cnt; j += 256) atomicAdd(&hist[stage[j] >> 17], 1);
    __syncthreads();
    offs[t] = hist[t];
    __syncthreads();
    for (int off = 1; off < 256; off <<= 1) {
        int v = (t >= off) ? offs[t - off] : 0;
        __syncthreads();
        offs[t] += v;
        __syncthreads();
    }
    int excl = offs[t] - hist[t];
    cur[t] = excl;
    int node = b * 256 + t;
    if (node < N_NODES) {
        rs[node] = base + excl;
        re[node] = base + excl + hist[t];
        dinv[node] = rsqrtf((float)(hist[t] + 1));   // +1 self loop
    }
    __syncthreads();
    for (int j = t; j < cnt; j += 256) {
        unsigned p = stage[j];
        int slot = atomicAdd(&cur[p >> 17], 1);
        csr[base + slot] = p & 0x1FFFFu;             // pure src
    }
}

// ---------------------------------------------------------------------------
// k_ab_h (R8 verbatim): bb = [x1 | tile(x2)] @ W4^T + b4
//         h0 = dinv * (Wg @ [relu(x1@W1^T+b1) | bb])
//         bins += W3[15:34].bb   (iteration-invariant output part)
// ---------------------------------------------------------------------------
__global__ __launch_bounds__(256) void k_ab_h(const float* __restrict__ x1, const float* __restrict__ x2,
                                              const float* __restrict__ W1, const float* __restrict__ b1,
                                              const float* __restrict__ W4, const float* __restrict__ b4,
                                              const float* __restrict__ Wg, const float* __restrict__ W3,
                                              const float* __restrict__ dinv,
                                              float* __restrict__ bb, float* __restrict__ h0,
                                              float* __restrict__ bins) {
    __shared__ float sW1[225], sb1[15], sW4[361], sb4[19], sWg[510], sW3b[19];
    for (int t = threadIdx.x; t < 225; t += 256) sW1[t] = W1[t];
    for (int t = threadIdx.x; t < 361; t += 256) sW4[t] = W4[t];
    for (int t = threadIdx.x; t < 510; t += 256) sWg[t] = Wg[t];
    if (threadIdx.x < 15) sb1[threadIdx.x] = b1[threadIdx.x];
    if (threadIdx.x < 19) { sb4[threadIdx.x] = b4[threadIdx.x]; sW3b[threadIdx.x] = W3[15 + threadIdx.x]; }
    __syncthreads();
    int i = blockIdx.x * 256 + threadIdx.x;
    bool valid = i < N_NODES;
    int ii = valid ? i : 0;
    float x[15];
#pragma unroll
    for (int k = 0; k < 15; k++) x[k] = x1[(size_t)ii * 15 + k];
    float xt[4];
    int ib = ii % N_BASE;
#pragma unroll
    for (int k = 0; k < 4; k++) xt[k] = x2[(size_t)ib * 4 + k];
    float in[34];
    float bp = 0.0f;
#pragma unroll
    for (int o = 0; o < 19; o++) {
        float s = sb4[o];
#pragma unroll
        for (int k = 0; k < 15; k++) s += x[k] * sW4[o * 19 + k];
#pragma unroll
        for (int k = 0; k < 4; k++) s += xt[k] * sW4[o * 19 + 15 + k];
        in[15 + o] = s;
        bp += s * sW3b[o];
        if (valid) bb[(size_t)ii * 20 + o] = s;
    }
#pragma unroll
    for (int o = 0; o < 15; o++) {
        float s = sb1[o];
#pragma unroll
        for (int k = 0; k < 15; k++) s += x[k] * sW1[o * 15 + k];
        in[o] = fmaxf(s, 0.0f);
    }
    float dn = dinv[ii];
    if (valid) {
#pragma unroll
        for (int o = 0; o < 15; o++) {
            float s = 0.0f;
#pragma unroll
            for (int k = 0; k < 34; k++) s += in[k] * sWg[o * 34 + k];
            h0[(size_t)ii * 16 + o] = s * dn;
        }
        h0[(size_t)ii * 16 + 15] = 0.0f;
    }
    float val = valid ? bp : 0.0f;
#pragma unroll
    for (int off = 32; off > 0; off >>= 1) val += __shfl_down(val, off, 64);
    __shared__ float wsum[4];
    if ((threadIdx.x & 63) == 0) wsum[threadIdx.x >> 6] = val;
    __syncthreads();
    if (threadIdx.x == 0) atomicAdd(&bins[blockIdx.x & 63], wsum[0] + wsum[1] + wsum[2] + wsum[3]);
}

// ---------------------------------------------------------------------------
// k_gather: one wave per dest node. Same FP sequence as R8/R9 (bit-exact):
// per 64-edge chunk, pre-shuffle indices and issue 2 groups of 8 INDEPENDENT
// predicated h-row loads into tmp[], then acc += tmp[i] in the original
// ascending-e0 order (inactive slots contribute +0.0f at the tail only).
// This raises per-wave loads-in-flight from ~2-4 to 8 without touching the
// summation tree.
// ---------------------------------------------------------------------------
__global__ __launch_bounds__(256) void k_gather(const int* __restrict__ rs, const int* __restrict__ re,
                                                const unsigned* __restrict__ csr,
                                                const float* __restrict__ h_in,
                                                const float* __restrict__ dinv,
                                                const float* __restrict__ bb,
                                                const float* __restrict__ Wg,
                                                const float* __restrict__ bg,
                                                const float* __restrict__ W3,
                                                float* __restrict__ h_out,
                                                float* __restrict__ bins, int last) {
    __shared__ float sWg[544], sbg[16], sW3[16];
    __shared__ float ws2[4];
    int t = threadIdx.x;
    for (int k = t; k < 544; k += 256) sWg[k] = (k < 510) ? Wg[k] : 0.0f;
    if (t < 16) { sbg[t] = (t < 15) ? bg[t] : 0.0f; sW3[t] = (t < 15) ? W3[t] : 0.0f; }
    __syncthreads();
    int node = blockIdx.x * 4 + (t >> 6);
    int lane = t & 63, ch = lane & 15, q = lane >> 4;
    int start = rs[node];
    int deg = re[node] - start;
    float hs = h_in[(size_t)node * 16 + ch];   // self row, hoisted for overlap
    float acc = 0.0f;
    for (int base = 0; base < deg; base += 64) {
        int rem = deg - base;
        unsigned ce = 0;
        if (lane < rem) ce = csr[start + base + lane];
        int lim = rem < 64 ? rem : 64;
#pragma unroll
        for (int g = 0; g < 2; g++) {
            float tmp[8];
#pragma unroll
            for (int i = 0; i < 8; i++) {
                int e0 = q + 4 * (8 * g + i);
                unsigned p = __shfl(ce, e0, 64);
                tmp[i] = (e0 < lim) ? h_in[(size_t)(p & 0x1FFFFu) * 16 + ch] : 0.0f;
            }
#pragma unroll
            for (int i = 0; i < 8; i++) acc += tmp[i];
        }
    }
    acc += __shfl_xor(acc, 16, 64);
    acc += __shfl_xor(acc, 32, 64);
    float dn = dinv[node];
    float aval = fmaxf(dn * (hs + acc) + sbg[ch], 0.0f);   // a[ch]; ch==15 -> 0
    if (!last) {
        float ink[15];
#pragma unroll
        for (int k = 0; k < 15; k++) ink[k] = __shfl(aval, k, 64);
        const float4* bp4 = (const float4*)(bb + (size_t)node * 20);
        float4 q0 = bp4[0], q1 = bp4[1], q2 = bp4[2], q3 = bp4[3], q4 = bp4[4];
        float bv[19] = {q0.x, q0.y, q0.z, q0.w, q1.x, q1.y, q1.z, q1.w,
                        q2.x, q2.y, q2.z, q2.w, q3.x, q3.y, q3.z, q3.w,
                        q4.x, q4.y, q4.z};
        float s = 0.0f;
#pragma unroll
        for (int k = 0; k < 15; k++) s += ink[k] * sWg[ch * 34 + k];
#pragma unroll
        for (int k = 0; k < 19; k++) s += bv[k] * sWg[ch * 34 + 15 + k];
        if (q == 0) h_out[(size_t)node * 16 + ch] = s * dn;   // ch==15 row: sWg pad -> 0
    } else {
        float c = aval * sW3[ch];
        c += __shfl_xor(c, 8, 64);
        c += __shfl_xor(c, 4, 64);
        c += __shfl_xor(c, 2, 64);
        c += __shfl_xor(c, 1, 64);
        if (lane == 0) ws2[t >> 6] = c;
        __syncthreads();
        if (t == 0) atomicAdd(&bins[blockIdx.x & 63], ws2[0] + ws2[1] + ws2[2] + ws2[3]);
    }
}

__global__ void k_finalize(const float* __restrict__ bins, const float* __restrict__ b3,
                           float* __restrict__ out) {
    float s = 0.0f;
    for (int k = 0; k < 64; k++) s += bins[k];
    out[0] = tanhf(s * (1.0f / (float)N_NODES) + b3[0]);
}

// ---------------------------------------------------------------------------
extern "C" void kernel_launch(void* const* d_in, const int* in_sizes, int n_in,
                              void* d_out, int out_size, void* d_ws, size_t ws_size,
                              hipStream_t stream) {
    const float* x1 = (const float*)d_in[0];
    const float* x2 = (const float*)d_in[1];
    const int* edges = (const int*)d_in[2];
    const float* W1 = (const float*)d_in[3];
    const float* b1 = (const float*)d_in[4];
    const float* Wg = (const float*)d_in[5];
    const float* bg = (const float*)d_in[6];
    const float* W3 = (const float*)d_in[7];
    const float* b3 = (const float*)d_in[8];
    const float* W4 = (const float*)d_in[9];
    const float* b4 = (const float*)d_in[10];

    const int* row = edges;             // edges[0]
    const int* col = edges + N_EDGES;   // edges[1]

    // workspace layout — ~36.9 MB (proven envelope >= 40.4 MB).
    char* ws = (char*)d_ws;
    unsigned* csr  = (unsigned*)ws;                              // NBKT*CAPB  (14.81 MB)
    float*    bb   = (float*)(csr + (size_t)NBKT * CAPB);        // N*20       (8.0 MB)
    float*    h0   = bb + (size_t)N_NODES * 20;                  // N*16       (6.4 MB)
    float*    h1   = h0 + (size_t)N_NODES * 16;                  // N*16       (6.4 MB)
    float*    dinv = h1 + (size_t)N_NODES * 16;                  // N
    int*      rs   = (int*)(dinv + N_NODES);                     // N
    int*      re   = rs + N_NODES;                               // N
    int*      gcur = re + N_NODES;                               // NBKT
    float*    bins = (float*)(gcur + NBKT);                      // 64

    int gN = (N_NODES + 255) / 256;                              // 391
    int gE = (N_EDGES + 8191) / 8192;                            // 391

    k_initg<<<1, 512, 0, stream>>>(gcur, bins);
    k_bucket<<<gE, 256, 0, stream>>>(row, col, gcur, csr);
    k_sort<<<NBKT, 256, 0, stream>>>(gcur, csr, rs, re, dinv);
    k_ab_h<<<gN, 256, 0, stream>>>(x1, x2, W1, b1, W4, b4, Wg, W3, dinv, bb, h0, bins);
    for (int t = 0; t < 5; t++) {
        const float* hi = (t & 1) ? h1 : h0;
        float* ho = (t & 1) ? h0 : h1;
        k_gather<<<N_NODES / 4, 256, 0, stream>>>(rs, re, csr, hi, dinv, bb, Wg, bg, W3,
                                                  ho, bins, t == 4 ? 1 : 0);
    }
    k_finalize<<<1, 1, 0, stream>>>(bins, b3, (float*)d_out);
}